// Round 10
// baseline (592.520 us; speedup 1.0000x reference)
//
#include <hip/hip_runtime.h>
#include <stdint.h>

// ---------------------------------------------------------------------------
// Fused transformer block: LN1 -> qkv -> causal flash attn -> out-proj(+res)
//                          -> LN2 -> gelu-FFN(+res) -> halt head
// bf16 MFMA (16x16x32) for all matmuls; fp32 residual stream.
// R15: gemm256 v3 for ff1 only; rest = banked R14 (560us) config.
//   v3 fixes R12/13's cross-wave race: vmcnt is PER-WAVE, the LDS tile is
//   filled by ALL waves -> ds_reads are safe only after a barrier that
//   post-dates every wave's vmcnt wait. Schedule per K-tile (4 phases):
//     ph0: stage 4 (A halves of kt+1) -> vmcnt(4) [12 outstanding -> drains
//          tile kt's 8] -> s_barrier (globally resident) -> ds_read ->
//          lgkm(0)+sched_barrier -> 16 MFMA -> barrier
//     ph1: stage 4 (B halves) -> ds_read -> barrier -> lgkm(0) -> MFMA -> barrier
//     ph2/3: ds_read -> barrier -> lgkm(0) -> MFMA -> barrier
//   Front-loaded staging gives the freshest load ~3 phases of slack.
//   Indexing identical to R11 (which PASSED refcheck; only schedule changed).
// ---------------------------------------------------------------------------

typedef unsigned short u16;
typedef __attribute__((ext_vector_type(8))) short short8v;   // 8 bf16 = 4 VGPR
typedef __attribute__((ext_vector_type(4))) float f32x4;     // MFMA C/D frag
typedef __attribute__((ext_vector_type(4))) u16 u16x4;

#define B_ 4
#define N_ 2048
#define D_ 1024
#define H_ 16
#define DH_ 64
#define ROWS_ (B_ * N_)   // 8192

__device__ __forceinline__ u16 f2bf(float f) {
  union { float f; unsigned u; } v; v.f = f;
  unsigned r = v.u + 0x7fffu + ((v.u >> 16) & 1u);   // RNE
  return (u16)(r >> 16);
}

// MFMA via inline asm. C operand from a previous MFMA or far-away init.
__device__ __forceinline__ f32x4 mfma_b(short8v a, short8v b, f32x4 c) {
  asm volatile("v_mfma_f32_16x16x32_bf16 %0, %1, %2, %0" : "+v"(c) : "v"(a), "v"(b));
  return c;
}
// C freshly VALU-written (zero init): cover the write->MFMA-read hazard.
__device__ __forceinline__ f32x4 mfma_b_vc(short8v a, short8v b, f32x4 c) {
  asm volatile("s_nop 1\n\tv_mfma_f32_16x16x32_bf16 %0, %1, %2, %0" : "+v"(c) : "v"(a), "v"(b));
  return c;
}
// Pass-through fence before VALU reads of MFMA results.
__device__ __forceinline__ f32x4 accfence(f32x4 v) {
  asm volatile("s_nop 7" : "+v"(v));
  return v;
}

// async global->LDS, 16B per lane. LDS side must be wave-uniform base + lane*16.
__device__ __forceinline__ void async16(const void* g, void* l) {
  __builtin_amdgcn_global_load_lds((__attribute__((address_space(1))) unsigned int*)g,
                                   (__attribute__((address_space(3))) unsigned int*)l,
                                   16, 0, 0);
}

// XOR swizzle for LDS tiles with CH 16B-chunks per row: physical chunk p of
// row r holds logical chunk p ^ (r & (CH-1)). Staging writes at lane*16
// (async16-compatible); reads of a fixed logical chunk across rows spread
// over CH distinct 16B slots.
#define SWZ8(row, chunk) ((((chunk) ^ ((row) & 7)) << 3))   // u16 offset in row

// ---------------------------------------------------------------------------
// LayerNorm over D=1024, fp32 in -> bf16 out. One block (256 thr) per row.
// ---------------------------------------------------------------------------
__global__ __launch_bounds__(256) void ln_kernel(const float* __restrict__ x,
    const float* __restrict__ gam, const float* __restrict__ bet,
    u16* __restrict__ out) {
  const int row = blockIdx.x;
  const int t = threadIdx.x;
  const float4 v = ((const float4*)(x + (size_t)row * D_))[t];
  float s  = v.x + v.y + v.z + v.w;
  float ss = v.x*v.x + v.y*v.y + v.z*v.z + v.w*v.w;
#pragma unroll
  for (int o = 32; o >= 1; o >>= 1) { s += __shfl_xor(s, o); ss += __shfl_xor(ss, o); }
  __shared__ float red[8];
  const int w = t >> 6;
  if ((t & 63) == 0) { red[w] = s; red[4 + w] = ss; }
  __syncthreads();
  s  = red[0] + red[1] + red[2] + red[3];
  ss = red[4] + red[5] + red[6] + red[7];
  const float mean = s * (1.0f / D_);
  const float var  = ss * (1.0f / D_) - mean * mean;
  const float rstd = rsqrtf(var + 1e-5f);
  const float4 g4 = ((const float4*)gam)[t];
  const float4 b4 = ((const float4*)bet)[t];
  u16x4 o4;
  o4.x = f2bf((v.x - mean) * rstd * g4.x + b4.x);
  o4.y = f2bf((v.y - mean) * rstd * g4.y + b4.y);
  o4.z = f2bf((v.z - mean) * rstd * g4.z + b4.z);
  o4.w = f2bf((v.w - mean) * rstd * g4.w + b4.w);
  *(u16x4*)(out + (size_t)row * D_ + t * 4) = o4;
}

// ---------------------------------------------------------------------------
// All 4 weight transposes in one launch: W[K][N] fp32 -> WT[N][K] bf16.
// ---------------------------------------------------------------------------
__global__ __launch_bounds__(256) void transpose_all(
    const float* __restrict__ wqkv, const float* __restrict__ wout,
    const float* __restrict__ wff1, const float* __restrict__ wff2,
    u16* __restrict__ wqkvT, u16* __restrict__ woutT,
    u16* __restrict__ wff1T, u16* __restrict__ wff2T) {
  __shared__ float tile[32][33];
  int id = blockIdx.x;
  const float* W; u16* WT; int K, N, nt, kt;
  if (id < 3072)      { W = wqkv; WT = wqkvT; K = 1024; N = 3072; nt = id % 96;  kt = id / 96; }
  else if (id < 4096) { id -= 3072; W = wout; WT = woutT; K = 1024; N = 1024; nt = id % 32;  kt = id / 32; }
  else if (id < 8192) { id -= 4096; W = wff1; WT = wff1T; K = 1024; N = 4096; nt = id % 128; kt = id / 128; }
  else                { id -= 8192; W = wff2; WT = wff2T; K = 4096; N = 1024; nt = id % 32;  kt = id / 32; }
  const int n0 = nt * 32, k0 = kt * 32;
  const int tx = threadIdx.x, ty = threadIdx.y;
#pragma unroll
  for (int i = 0; i < 4; ++i)
    tile[ty + i * 8][tx] = W[(size_t)(k0 + ty + i * 8) * N + n0 + tx];
  __syncthreads();
#pragma unroll
  for (int i = 0; i < 4; ++i)
    WT[(size_t)(n0 + ty + i * 8) * K + k0 + tx] = f2bf(tile[tx][ty + i * 8]);
}

// V transpose: qkv bf16 v-part -> vt[b][h][d][n] so PV A-frags read contiguous.
__global__ __launch_bounds__(256) void transpose_v(const u16* __restrict__ qkv,
    u16* __restrict__ vt) {
  __shared__ u16 tile[32][33];
  const int bh = blockIdx.z;
  const int bb = bh >> 4, hh = bh & 15;
  const int n0 = blockIdx.x * 32, d0 = blockIdx.y * 32;
  const int tx = threadIdx.x, ty = threadIdx.y;
#pragma unroll
  for (int i = 0; i < 4; ++i)
    tile[ty + i * 8][tx] =
        qkv[(size_t)(bb * N_ + n0 + ty + i * 8) * 3072 + 2048 + hh * DH_ + d0 + tx];
  __syncthreads();
#pragma unroll
  for (int i = 0; i < 4; ++i)
    vt[((size_t)bh * DH_ + d0 + ty + i * 8) * N_ + n0 + tx] = tile[tx][ty + i * 8];
}

// ---------------------------------------------------------------------------
// 256x256 bf16 GEMM v3 (race-free counted-vmcnt 4-phase schedule; see top).
// 512 threads = 8 waves (2M x 4N); per-wave output 128x64 = acc[8][4].
// BK=64; LDS 128KB: As/Bs [2 dbuf][2 half][128*64] swizzled (CH=8).
// Raw s_barrier keeps prefetch loads in flight (__syncthreads would drain).
// Epilogue modes: 0 = bf16 store, 2 = gelu(C+bias) -> bf16.
// ---------------------------------------------------------------------------
__global__ __launch_bounds__(512) void gemm256(
    const u16* __restrict__ A, const u16* __restrict__ BT,
    int N, int K, int mode, int gx, int rw,
    const float* __restrict__ bias, u16* __restrict__ outb) {
  __shared__ alignas(16) u16 As[2][2][128 * 64];   // [dbuf][half][row*64]
  __shared__ alignas(16) u16 Bs[2][2][128 * 64];
  const int t = threadIdx.x;
  const int lane = t & 63, w = t >> 6;
  const int wm = w >> 2, wn = w & 3;         // 2 x 4 wave grid
  const int cc = lane & 15, quad = lane >> 4;
  const int hb = wn >> 1, lb = (wn & 1) * 64;   // B half + local base row

  // 2D-region XCD decode (bijective: gridDim.x % 8 == 0, rw | gx, rw | q)
  const int i   = blockIdx.x;
  const int xcd = i & 7;
  const int s   = i >> 3;
  const int rcols = gx / rw;
  const int rh  = (gridDim.x >> 3) / rw;
  const int rcol = xcd % rcols, rrow = xcd / rcols;
  const int lx = s % rw, ly = s / rw;
  const int n0 = (rcol * rw + lx) * 256;
  const int m0 = (rrow * rh + ly) * 256;

  const f32x4 fz = {0.f, 0.f, 0.f, 0.f};
  f32x4 acc[8][4];
#pragma unroll
  for (int i2 = 0; i2 < 8; ++i2)
#pragma unroll
    for (int j = 0; j < 4; ++j) acc[i2][j] = fz;

  const int t16 = t * 16;
  // prologue: all 4 halves of tile 0 -> buf 0  (8 loads/thread)
#pragma unroll
  for (int h = 0; h < 2; ++h)
#pragma unroll
    for (int pass = 0; pass < 2; ++pass) {
      const int off = pass * 8192 + t16;     // byte offset in 16KB half
      const int row = off >> 7;              // 128B rows (64 bf16)
      const int cl  = ((off >> 4) & 7) ^ (row & 7);
      async16(A  + (size_t)(m0 + h * 128 + row) * K + cl * 8,
              (char*)&As[0][h][0] + off);
      async16(BT + (size_t)(n0 + h * 128 + row) * K + cl * 8,
              (char*)&Bs[0][h][0] + off);
    }

  const int NT = K >> 6;
  for (int kt = 0; kt < NT; ++kt) {
    const int cur = kt & 1, nxt = cur ^ 1;
    const bool more = (kt + 1 < NT);
    const int k1 = (kt + 1) << 6;
#pragma unroll
    for (int ph = 0; ph < 4; ++ph) {
      // --- staging: front-loaded. ph0: both A halves (4 loads);
      //     ph1: both B halves (4 loads); ph2/3: none.
      if (more && ph == 0) {
#pragma unroll
        for (int h = 0; h < 2; ++h)
#pragma unroll
          for (int pass = 0; pass < 2; ++pass) {
            const int off = pass * 8192 + t16;
            const int row = off >> 7;
            const int cl  = ((off >> 4) & 7) ^ (row & 7);
            async16(A + (size_t)(m0 + h * 128 + row) * K + k1 + cl * 8,
                    (char*)&As[nxt][h][0] + off);
          }
      }
      if (more && ph == 1) {
#pragma unroll
        for (int h = 0; h < 2; ++h)
#pragma unroll
          for (int pass = 0; pass < 2; ++pass) {
            const int off = pass * 8192 + t16;
            const int row = off >> 7;
            const int cl  = ((off >> 4) & 7) ^ (row & 7);
            async16(BT + (size_t)(n0 + h * 128 + row) * K + k1 + cl * 8,
                    (char*)&Bs[nxt][h][0] + off);
          }
      }
      // --- ph0 residency gate: per-wave drain of tile kt, THEN barrier so
      //     ALL waves' fills are visible before any ds_read of tile kt.
      if (ph == 0) {
        if (more) asm volatile("s_waitcnt vmcnt(4)" ::: "memory");
        else      asm volatile("s_waitcnt vmcnt(0)" ::: "memory");
        __builtin_amdgcn_s_barrier();
        __builtin_amdgcn_sched_barrier(0);   // no ds_read hoists above gate
      }
      // --- this quadrant's fragments (ph1-3: issued before leading barrier)
      const int kk = ph >> 1, rh2 = ph & 1;
      short8v a[4], b[4];
#pragma unroll
      for (int i2 = 0; i2 < 4; ++i2)
        a[i2] = *(const short8v*)(&As[cur][wm][((rh2 * 4 + i2) * 16 + cc) * 64 +
                                               SWZ8(cc, kk * 4 + quad)]);
#pragma unroll
      for (int j = 0; j < 4; ++j)
        b[j] = *(const short8v*)(&Bs[cur][hb][(lb + j * 16 + cc) * 64 +
                                              SWZ8(cc, kk * 4 + quad)]);
      // --- leading barrier (ph1-3; ph0 already gated), own-read drain, pin
      if (ph != 0) __builtin_amdgcn_s_barrier();
      asm volatile("s_waitcnt lgkmcnt(0)" ::: "memory");
      __builtin_amdgcn_sched_barrier(0);
      // --- MFMA cluster
      __builtin_amdgcn_s_setprio(1);
#pragma unroll
      for (int i2 = 0; i2 < 4; ++i2)
#pragma unroll
        for (int j = 0; j < 4; ++j)
          acc[rh2 * 4 + i2][j] = mfma_b(a[i2], b[j], acc[rh2 * 4 + i2][j]);
      __builtin_amdgcn_s_setprio(0);
      // --- trailing barrier (all reads of buf cur lgkm-drained before any
      //     wave can reach the next tile's stages of buf cur)
      __builtin_amdgcn_s_barrier();
    }
  }

#pragma unroll
  for (int i2 = 0; i2 < 8; ++i2) {
    const int row = m0 + wm * 128 + i2 * 16 + quad * 4;
#pragma unroll
    for (int j = 0; j < 4; ++j) {
      const int col = n0 + wn * 64 + j * 16 + cc;
      f32x4 v = accfence(acc[i2][j]);
#pragma unroll
      for (int r = 0; r < 4; ++r) {
        const size_t idx = (size_t)(row + r) * N + col;
        float val = v[r];
        if (mode == 2) {
          val += bias[col];
          const float zz = val * fmaf(val * val, 0.044715f, 1.0f);
          const float e = __builtin_amdgcn_exp2f(-2.3022082f * zz);
          val = val * __builtin_amdgcn_rcpf(1.0f + e);
        }
        outb[idx] = f2bf(val);
      }
    }
  }
}

// ---------------------------------------------------------------------------
// bf16 MFMA GEMM: 128x128 block tile, templated BK (64 or 128), XOR-swizzled
// LDS, single-buffered stage->sync->compute->sync (drain covered by TLP;
// __syncthreads = per-wave vmcnt(0) + barrier = globally safe).
// Epilogue modes: 0 bf16; 2 gelu->bf16; 1/3 C+bias+res -> fp32.
// ---------------------------------------------------------------------------
template <int BK>
__global__ __launch_bounds__(256) void gemm_bt(
    const u16* __restrict__ A, const u16* __restrict__ BT,
    int N, int K, int mode, int gx, int rw,
    const float* __restrict__ bias, const float* __restrict__ res,
    float* __restrict__ outf, u16* __restrict__ outb) {
  constexpr int ROWB = BK * 2;       // bytes per LDS row
  constexpr int CH   = BK / 8;       // 16B chunks per row (8 or 16)
  __shared__ alignas(16) u16 As[128 * BK];
  __shared__ alignas(16) u16 Bs[128 * BK];
  const int t = threadIdx.x;
  const int lane = t & 63, w = t >> 6;
  const int wm = w >> 1, wn = w & 1;
  const int cc = lane & 15, quad = lane >> 4;

  const int i   = blockIdx.x;
  const int xcd = i & 7;
  const int s   = i >> 3;
  const int rcols = gx / rw;
  const int rh  = (gridDim.x >> 3) / rw;
  const int rcol = xcd % rcols, rrow = xcd / rcols;
  const int lx = s % rw, ly = s / rw;
  const int n0 = (rcol * rw + lx) * 128;
  const int m0 = (rrow * rh + ly) * 128;

  const f32x4 fz = {0.f, 0.f, 0.f, 0.f};
  f32x4 acc[4][4];
#pragma unroll
  for (int i2 = 0; i2 < 4; ++i2)
#pragma unroll
    for (int j = 0; j < 4; ++j) acc[i2][j] = fz;

  const int off0 = t * 16;
  for (int k0 = 0; k0 < K; k0 += BK) {
#pragma unroll
    for (int r = 0; r < BK / 16; ++r) {
      const int off = r * 4096 + off0;
      const int row = off / ROWB;
      const int cl  = ((off >> 4) & (CH - 1)) ^ (row & (CH - 1));
      async16(A  + (size_t)(m0 + row) * K + k0 + cl * 8, (char*)As + off);
      async16(BT + (size_t)(n0 + row) * K + k0 + cl * 8, (char*)Bs + off);
    }
    __syncthreads();   // drains vmcnt (all waves) -> tiles resident
#pragma unroll
    for (int kk = 0; kk < BK / 32; ++kk) {
      short8v a[4], b[4];
#pragma unroll
      for (int i2 = 0; i2 < 4; ++i2)
        a[i2] = *(const short8v*)(As + (wm * 64 + i2 * 16 + cc) * BK +
                                  (((kk * 4 + quad) ^ (cc & (CH - 1))) << 3));
#pragma unroll
      for (int j = 0; j < 4; ++j)
        b[j] = *(const short8v*)(Bs + (wn * 64 + j * 16 + cc) * BK +
                                 (((kk * 4 + quad) ^ (cc & (CH - 1))) << 3));
#pragma unroll
      for (int i2 = 0; i2 < 4; ++i2)
#pragma unroll
        for (int j = 0; j < 4; ++j) acc[i2][j] = mfma_b(a[i2], b[j], acc[i2][j]);
    }
    __syncthreads();
  }

#pragma unroll
  for (int i2 = 0; i2 < 4; ++i2) {
    const int row = m0 + wm * 64 + i2 * 16 + quad * 4;
#pragma unroll
    for (int j = 0; j < 4; ++j) {
      const int col = n0 + wn * 64 + j * 16 + cc;
      f32x4 v = accfence(acc[i2][j]);
#pragma unroll
      for (int r = 0; r < 4; ++r) {
        const size_t idx = (size_t)(row + r) * N + col;
        float val = v[r];
        if (mode == 0) {
          outb[idx] = f2bf(val);
        } else if (mode == 2) {
          val += bias[col];
          const float zz = val * fmaf(val * val, 0.044715f, 1.0f);
          const float e = __builtin_amdgcn_exp2f(-2.3022082f * zz);
          val = val * __builtin_amdgcn_rcpf(1.0f + e);
          outb[idx] = f2bf(val);
        } else {  // 1 or 3: fp32 residual epilogue
          outf[idx] = val + bias[col] + res[idx];
        }
      }
    }
  }
}

// ---------------------------------------------------------------------------
// Causal flash attention (R7 structure): uniform chunk-pair blocks,
// XCD-local decode, double-buffered async16 K/V staging.
// ---------------------------------------------------------------------------
__global__ __launch_bounds__(256, 2) void attn_kernel(const u16* __restrict__ qkv,
    const u16* __restrict__ vt, u16* __restrict__ outp) {
  const int f  = blockIdx.x;            // 0..511
  const int p  = (f >> 3) & 7;          // chunk pair: {p, 15-p}
  const int g  = ((f >> 6) << 3) | (f & 7);   // (b,h) group, XCD-local mod 8
  const int hh = g & 15, bb = g >> 4;
  const int t = threadIdx.x, lane = t & 63, w = t >> 6;
  const int cc = lane & 15, quad = lane >> 4;

  __shared__ alignas(16) u16 Ks[2][64 * 64];   // [key][d], swizzled, 8KB each
  __shared__ alignas(16) u16 Vs[2][64 * 64];   // [d][key], swizzled
  __shared__ alignas(16) u16 Ps[4][16 * 64];   // per-wave P round-trip, swizzled

  const u16* kbase = qkv + (size_t)bb * N_ * 3072 + 1024 + hh * DH_;
  const u16* vbase = vt + ((size_t)(bb * H_ + hh)) * DH_ * N_;

  const int soff0 = t * 16;
#pragma unroll
  for (int r = 0; r < 2; ++r) {      // prologue: K/V tile 0 -> buf 0
    const int off = r * 4096 + soff0;
    const int row = off >> 7;
    const int cl  = ((off >> 4) & 7) ^ (row & 7);
    async16(kbase + (size_t)row * 3072 + cl * 8, (char*)Ks[0] + off);
    async16(vbase + (size_t)row * N_ + cl * 8,   (char*)Vs[0] + off);
  }

  const f32x4 fz = {0.f, 0.f, 0.f, 0.f};
  const float C1 = 0.18033688011112042f;    // 0.125 * log2(e)
  const float C2 = -11.541560327111707f;    // -8 * log2(e)

  int bufc = 0;
#pragma unroll
  for (int ci = 0; ci < 2; ++ci) {
    const int qc = ci ? 15 - p : p;
    const int q0 = qc * 128;
    const int ktmax = 2 * qc + 1;

    short8v qa[2][2];
#pragma unroll
    for (int s = 0; s < 2; ++s)
#pragma unroll
      for (int h = 0; h < 2; ++h)
        qa[s][h] = *(const short8v*)(qkv +
            (size_t)(bb * N_ + q0 + s * 64 + w * 16 + cc) * 3072 +
            hh * DH_ + h * 32 + quad * 8);

    f32x4 of[2][4];
    float rs[2][4];
#pragma unroll
    for (int s = 0; s < 2; ++s)
#pragma unroll
      for (int n = 0; n < 4; ++n) { of[s][n] = fz; rs[s][n] = 0.f; }

    for (int kt = 0; kt <= ktmax; ++kt) {
      const int k0 = kt * 64;
      const int cur = bufc & 1;
      __syncthreads();   // drains async16 for buf cur; buf cur^1 is now free

      if ((kt < ktmax) | (ci == 0)) {
        const int k1 = (kt < ktmax) ? k0 + 64 : 0;
#pragma unroll
        for (int r = 0; r < 2; ++r) {
          const int off = r * 4096 + soff0;
          const int row = off >> 7;
          const int cl  = ((off >> 4) & 7) ^ (row & 7);
          async16(kbase + (size_t)(k1 + row) * 3072 + cl * 8, (char*)Ks[cur ^ 1] + off);
          async16(vbase + (size_t)row * N_ + k1 + cl * 8,     (char*)Vs[cur ^ 1] + off);
        }
      }

      const u16* KsB = Ks[cur];
      const u16* VsB = Vs[cur];
      short8v kb[4][2], vb[4][2];
#pragma unroll
      for (int j = 0; j < 4; ++j)
#pragma unroll
        for (int h = 0; h < 2; ++h) {
          kb[j][h] = *(const short8v*)(KsB + (j * 16 + cc) * 64 + SWZ8(cc, h * 4 + quad));
          vb[j][h] = *(const short8v*)(VsB + (j * 16 + cc) * 64 + SWZ8(cc, h * 4 + quad));
        }

#pragma unroll
      for (int s = 0; s < 2; ++s) {
        const int Rbase = q0 + s * 64 + w * 16;
        if (k0 > Rbase + 15) continue;

        f32x4 sr[4];
#pragma unroll
        for (int j = 0; j < 4; ++j) {
          f32x4 z = fz;
          z = mfma_b_vc(qa[s][0], kb[j][0], z);
          z = mfma_b(qa[s][1], kb[j][1], z);
          sr[j] = accfence(z);
        }

        if (k0 + 63 > Rbase) {
#pragma unroll
          for (int j = 0; j < 4; ++j) {
            const int kcol = k0 + j * 16 + cc;
#pragma unroll
            for (int r = 0; r < 4; ++r) {
              float pv = __builtin_amdgcn_exp2f(fmaf(sr[j][r], C1, C2));
              pv = (kcol <= Rbase + quad * 4 + r) ? pv : 0.f;
              sr[j][r] = pv;
              rs[s][r] += pv;
            }
          }
        } else {
#pragma unroll
          for (int j = 0; j < 4; ++j)
#pragma unroll
            for (int r = 0; r < 4; ++r) {
              const float pv = __builtin_amdgcn_exp2f(fmaf(sr[j][r], C1, C2));
              sr[j][r] = pv;
              rs[s][r] += pv;
            }
        }

#pragma unroll
        for (int j = 0; j < 4; ++j)
#pragma unroll
          for (int r = 0; r < 4; ++r) {
            union { float f; unsigned u; } cv; cv.f = sr[j][r];
            const int rho = quad * 4 + r;
            const int Lc  = j * 2 + (cc >> 3);
            Ps[w][rho * 64 + (((Lc ^ (rho & 7)) << 3) | (cc & 7))] =
                (u16)((cv.u + 0x8000u) >> 16);
          }
        const short8v pa0 = *(const short8v*)(&Ps[w][cc * 64 + SWZ8(cc, quad)]);
        const short8v pa1 = *(const short8v*)(&Ps[w][cc * 64 + SWZ8(cc, 4 + quad)]);
#pragma unroll
        for (int n = 0; n < 4; ++n) {
          of[s][n] = mfma_b(pa0, vb[n][0], of[s][n]);
          of[s][n] = mfma_b(pa1, vb[n][1], of[s][n]);
        }
      }
      ++bufc;
    }

#pragma unroll
    for (int o = 1; o < 16; o <<= 1)
#pragma unroll
      for (int s = 0; s < 2; ++s)
#pragma unroll
        for (int r = 0; r < 4; ++r) rs[s][r] += __shfl_xor(rs[s][r], o);

#pragma unroll
    for (int s = 0; s < 2; ++s) {
      float inv[4];
#pragma unroll
      for (int r = 0; r < 4; ++r) inv[r] = 1.0f / rs[s][r];
#pragma unroll
      for (int n = 0; n < 4; ++n) {
        f32x4 o = accfence(of[s][n]);
#pragma unroll
        for (int r = 0; r < 4; ++r) {
          const size_t row = (size_t)(bb * N_ + q0 + s * 64 + w * 16 + quad * 4 + r);
          outp[row * 1024 + hh * DH_ + n * 16 + cc] = f2bf(o[r] * inv[r]);
        }
      }
    }
  }
}

// ---------------------------------------------------------------------------
// Halt head: hout[b] = mean_n(x[b]) @ w_halt + b_halt
// ---------------------------------------------------------------------------
__global__ void halt_init(float* __restrict__ hout, const float* __restrict__ bh) {
  if (threadIdx.x < B_) hout[threadIdx.x] = bh[0];
}

__global__ __launch_bounds__(256) void halt_partial(const float* __restrict__ xf,
    const float* __restrict__ wh, float* __restrict__ hout) {
  const int bb = blockIdx.y, sl = blockIdx.x;
  const size_t base = ((size_t)bb * N_ + sl * 64) * D_;
  float p = 0.f;
  for (int e = threadIdx.x; e < 64 * D_; e += 256)
    p += xf[base + e] * wh[e & (D_ - 1)];
#pragma unroll
  for (int o = 32; o >= 1; o >>= 1) p += __shfl_xor(p, o);
  __shared__ float red[4];
  const int w = threadIdx.x >> 6;
  if ((threadIdx.x & 63) == 0) red[w] = p;
  __syncthreads();
  if (threadIdx.x == 0)
    atomicAdd(&hout[bb], (red[0] + red[1] + red[2] + red[3]) * (1.0f / N_));
}

// ---------------------------------------------------------------------------
extern "C" void kernel_launch(void* const* d_in, const int* in_sizes, int n_in,
                              void* d_out, int out_size, void* d_ws, size_t ws_size,
                              hipStream_t stream) {
  (void)in_sizes; (void)n_in; (void)out_size; (void)ws_size;
  const float* x      = (const float*)d_in[0];
  const float* ln1_g  = (const float*)d_in[1];
  const float* ln1_b  = (const float*)d_in[2];
  const float* w_qkv  = (const float*)d_in[3];
  const float* w_out  = (const float*)d_in[4];
  const float* b_out  = (const float*)d_in[5];
  const float* ln2_g  = (const float*)d_in[6];
  const float* ln2_b  = (const float*)d_in[7];
  const float* w_ff1  = (const float*)d_in[8];
  const float* b_ff1  = (const float*)d_in[9];
  const float* w_ff2  = (const float*)d_in[10];
  const float* b_ff2  = (const float*)d_in[11];
  const float* w_halt = (const float*)d_in[12];
  const float* b_halt = (const float*)d_in[13];

  float* out_x    = (float*)d_out;                       // [8192,1024] fp32
  float* out_halt = out_x + (size_t)ROWS_ * D_;          // [4]

  // Workspace layout (bytes). Persistent transposed bf16 weights, then a
  // liveness-overlapped scratch region. Total ~104 MB.
  char* ws = (char*)d_ws;
  u16* wqkvT = (u16*)(ws + 0);           //  6291456  [3072,1024]
  u16* woutT = (u16*)(ws + 6291456);     //  2097152  [1024,1024]
  u16* wff1T = (u16*)(ws + 8388608);     //  8388608  [4096,1024]
  u16* wff2T = (u16*)(ws + 16777216);    //  8388608  [1024,4096]
  char* RB   = ws + 25165824;
  u16* qkvb  = (u16*)(RB);               // 50331648  [8192,3072] (dead after attn)
  u16* h1    = (u16*)(RB + 50331648);    // 16777216  (dead after qkv gemm)
  u16* attno = h1;                       // aliases h1 (dead after out-proj)
  u16* vtb   = (u16*)(RB + 67108864);    // 16777216  (dead after attn)
  u16* h2    = (u16*)(RB);               // aliases qkvb
  u16* ff1b  = (u16*)(RB + 16777216);    // 67108864  aliases vtb/attno tail

  const dim3 tb(32, 8);
  // 1) weights -> bf16 transposed (single launch)
  transpose_all<<<12288, tb, 0, stream>>>(w_qkv, w_out, w_ff1, w_ff2,
                                          wqkvT, woutT, wff1T, wff2T);
  // 2) LN1
  ln_kernel<<<ROWS_, 256, 0, stream>>>(x, ln1_g, ln1_b, h1);
  // 3) qkv = h1 @ w_qkv -> bf16. grid 24x64=1536 tiles; region 12x16
  gemm_bt<64><<<1536, 256, 0, stream>>>(h1, wqkvT, 3072, 1024, 0, 24, 12,
                                        nullptr, nullptr, nullptr, qkvb);
  // 4) V -> [b,h,d,n]
  transpose_v<<<dim3(64, 2, 64), tb, 0, stream>>>(qkvb, vtb);
  // 5) causal flash attention (uniform chunk-pair blocks, XCD-local decode)
  attn_kernel<<<dim3(512), 256, 0, stream>>>(qkvb, vtb, attno);
  // 6) x1 = attn @ w_out + b_out + x. grid 8x64=512 tiles; region 8x8; BK=64
  gemm_bt<64><<<512, 256, 0, stream>>>(attno, woutT, 1024, 1024, 1, 8, 8,
                                       b_out, x, out_x, nullptr);
  // 7) LN2
  ln_kernel<<<ROWS_, 256, 0, stream>>>(out_x, ln2_g, ln2_b, h2);
  // 8) ff1 = gelu(h2 @ w_ff1 + b_ff1) -> bf16. 256^2: 32x16 = 512; region 8x8
  gemm256<<<512, 512, 0, stream>>>(h2, wff1T, 4096, 1024, 2, 16, 8,
                                   b_ff1, ff1b);
  // 9) x = ff1 @ w_ff2 + b_ff2 + x1. grid 8x64=512 tiles; region 8x8; BK=128
  gemm_bt<128><<<512, 256, 0, stream>>>(ff1b, wff2T, 1024, 4096, 3, 8, 8,
                                        b_ff2, out_x, out_x, nullptr);
  // 10) halt
  halt_init<<<1, 64, 0, stream>>>(out_halt, b_halt);
  halt_partial<<<dim3(32, 4), 256, 0, stream>>>(out_x, w_halt, out_halt);
}

// Round 11
// 580.011 us; speedup vs baseline: 1.0216x; 1.0216x over previous
//
#include <hip/hip_runtime.h>
#include <stdint.h>

// ---------------------------------------------------------------------------
// Fused transformer block: LN1 -> qkv -> causal flash attn -> out-proj(+res)
//                          -> LN2 -> gelu-FFN(+res) -> halt head
// bf16 MFMA (16x16x32) for all matmuls; fp32 residual stream.
// R16 == R14 banked config (560us, twice-reproduced). 256^2 counted-vmcnt
// GEMM retired after 3 attempts (R11 coarse 147us; R12/13 racy; R15
// race-free but 136us at MfmaUtil 21% — phase barriers serialize at
// 1 block/CU without the template's exact derived-wait overlap).
//   - qkv BK64 1536 blocks, out-proj BK64, ff1 128^2 BK64, ff2 BK128.
//   - Cheap tanh-gelu epilogue (R8); 2D-region XCD decode (R9);
//     uniform chunk-pair attn w/ XCD-local decode (R7).
// ---------------------------------------------------------------------------

typedef unsigned short u16;
typedef __attribute__((ext_vector_type(8))) short short8v;   // 8 bf16 = 4 VGPR
typedef __attribute__((ext_vector_type(4))) float f32x4;     // MFMA C/D frag
typedef __attribute__((ext_vector_type(4))) u16 u16x4;

#define B_ 4
#define N_ 2048
#define D_ 1024
#define H_ 16
#define DH_ 64
#define ROWS_ (B_ * N_)   // 8192

__device__ __forceinline__ u16 f2bf(float f) {
  union { float f; unsigned u; } v; v.f = f;
  unsigned r = v.u + 0x7fffu + ((v.u >> 16) & 1u);   // RNE
  return (u16)(r >> 16);
}

// MFMA via inline asm. C operand from a previous MFMA or far-away init.
__device__ __forceinline__ f32x4 mfma_b(short8v a, short8v b, f32x4 c) {
  asm volatile("v_mfma_f32_16x16x32_bf16 %0, %1, %2, %0" : "+v"(c) : "v"(a), "v"(b));
  return c;
}
// C freshly VALU-written (zero init): cover the write->MFMA-read hazard.
__device__ __forceinline__ f32x4 mfma_b_vc(short8v a, short8v b, f32x4 c) {
  asm volatile("s_nop 1\n\tv_mfma_f32_16x16x32_bf16 %0, %1, %2, %0" : "+v"(c) : "v"(a), "v"(b));
  return c;
}
// Pass-through fence before VALU reads of MFMA results.
__device__ __forceinline__ f32x4 accfence(f32x4 v) {
  asm volatile("s_nop 7" : "+v"(v));
  return v;
}

// async global->LDS, 16B per lane. LDS side must be wave-uniform base + lane*16.
__device__ __forceinline__ void async16(const void* g, void* l) {
  __builtin_amdgcn_global_load_lds((__attribute__((address_space(1))) unsigned int*)g,
                                   (__attribute__((address_space(3))) unsigned int*)l,
                                   16, 0, 0);
}

// XOR swizzle for LDS tiles with CH 16B-chunks per row: physical chunk p of
// row r holds logical chunk p ^ (r & (CH-1)). Staging writes at lane*16
// (async16-compatible); reads of a fixed logical chunk across rows spread
// over CH distinct 16B slots.
#define SWZ8(row, chunk) ((((chunk) ^ ((row) & 7)) << 3))   // u16 offset in row

// ---------------------------------------------------------------------------
// LayerNorm over D=1024, fp32 in -> bf16 out. One block (256 thr) per row.
// ---------------------------------------------------------------------------
__global__ __launch_bounds__(256) void ln_kernel(const float* __restrict__ x,
    const float* __restrict__ gam, const float* __restrict__ bet,
    u16* __restrict__ out) {
  const int row = blockIdx.x;
  const int t = threadIdx.x;
  const float4 v = ((const float4*)(x + (size_t)row * D_))[t];
  float s  = v.x + v.y + v.z + v.w;
  float ss = v.x*v.x + v.y*v.y + v.z*v.z + v.w*v.w;
#pragma unroll
  for (int o = 32; o >= 1; o >>= 1) { s += __shfl_xor(s, o); ss += __shfl_xor(ss, o); }
  __shared__ float red[8];
  const int w = t >> 6;
  if ((t & 63) == 0) { red[w] = s; red[4 + w] = ss; }
  __syncthreads();
  s  = red[0] + red[1] + red[2] + red[3];
  ss = red[4] + red[5] + red[6] + red[7];
  const float mean = s * (1.0f / D_);
  const float var  = ss * (1.0f / D_) - mean * mean;
  const float rstd = rsqrtf(var + 1e-5f);
  const float4 g4 = ((const float4*)gam)[t];
  const float4 b4 = ((const float4*)bet)[t];
  u16x4 o4;
  o4.x = f2bf((v.x - mean) * rstd * g4.x + b4.x);
  o4.y = f2bf((v.y - mean) * rstd * g4.y + b4.y);
  o4.z = f2bf((v.z - mean) * rstd * g4.z + b4.z);
  o4.w = f2bf((v.w - mean) * rstd * g4.w + b4.w);
  *(u16x4*)(out + (size_t)row * D_ + t * 4) = o4;
}

// ---------------------------------------------------------------------------
// All 4 weight transposes in one launch: W[K][N] fp32 -> WT[N][K] bf16.
// ---------------------------------------------------------------------------
__global__ __launch_bounds__(256) void transpose_all(
    const float* __restrict__ wqkv, const float* __restrict__ wout,
    const float* __restrict__ wff1, const float* __restrict__ wff2,
    u16* __restrict__ wqkvT, u16* __restrict__ woutT,
    u16* __restrict__ wff1T, u16* __restrict__ wff2T) {
  __shared__ float tile[32][33];
  int id = blockIdx.x;
  const float* W; u16* WT; int K, N, nt, kt;
  if (id < 3072)      { W = wqkv; WT = wqkvT; K = 1024; N = 3072; nt = id % 96;  kt = id / 96; }
  else if (id < 4096) { id -= 3072; W = wout; WT = woutT; K = 1024; N = 1024; nt = id % 32;  kt = id / 32; }
  else if (id < 8192) { id -= 4096; W = wff1; WT = wff1T; K = 1024; N = 4096; nt = id % 128; kt = id / 128; }
  else                { id -= 8192; W = wff2; WT = wff2T; K = 4096; N = 1024; nt = id % 32;  kt = id / 32; }
  const int n0 = nt * 32, k0 = kt * 32;
  const int tx = threadIdx.x, ty = threadIdx.y;
#pragma unroll
  for (int i = 0; i < 4; ++i)
    tile[ty + i * 8][tx] = W[(size_t)(k0 + ty + i * 8) * N + n0 + tx];
  __syncthreads();
#pragma unroll
  for (int i = 0; i < 4; ++i)
    WT[(size_t)(n0 + ty + i * 8) * K + k0 + tx] = f2bf(tile[tx][ty + i * 8]);
}

// V transpose: qkv bf16 v-part -> vt[b][h][d][n] so PV A-frags read contiguous.
__global__ __launch_bounds__(256) void transpose_v(const u16* __restrict__ qkv,
    u16* __restrict__ vt) {
  __shared__ u16 tile[32][33];
  const int bh = blockIdx.z;
  const int bb = bh >> 4, hh = bh & 15;
  const int n0 = blockIdx.x * 32, d0 = blockIdx.y * 32;
  const int tx = threadIdx.x, ty = threadIdx.y;
#pragma unroll
  for (int i = 0; i < 4; ++i)
    tile[ty + i * 8][tx] =
        qkv[(size_t)(bb * N_ + n0 + ty + i * 8) * 3072 + 2048 + hh * DH_ + d0 + tx];
  __syncthreads();
#pragma unroll
  for (int i = 0; i < 4; ++i)
    vt[((size_t)bh * DH_ + d0 + ty + i * 8) * N_ + n0 + tx] = tile[tx][ty + i * 8];
}

// ---------------------------------------------------------------------------
// bf16 MFMA GEMM: 128x128 block tile, templated BK (64 or 128), XOR-swizzled
// LDS, single-buffered stage->sync->compute->sync (drain covered by TLP;
// __syncthreads = per-wave vmcnt(0) + barrier = globally safe for the
// cross-wave LDS fill). 4 waves 2x2, each wave 4x4 16x16 frags.
// 1-D grid with 2D-region XCD decode: block id i -> xcd = i&7 owns a
// rw x rh region of the (n,m) tile grid, keeping operand panels in the
// XCD's private L2.
// Epilogue modes:
//   0: store bf16            2: gelu(C+bias) -> bf16   (tanh-form, exp2+rcp)
//   1/3: C + bias + res -> fp32
// ---------------------------------------------------------------------------
template <int BK>
__global__ __launch_bounds__(256) void gemm_bt(
    const u16* __restrict__ A, const u16* __restrict__ BT,
    int N, int K, int mode, int gx, int rw,
    const float* __restrict__ bias, const float* __restrict__ res,
    float* __restrict__ outf, u16* __restrict__ outb) {
  constexpr int ROWB = BK * 2;       // bytes per LDS row
  constexpr int CH   = BK / 8;       // 16B chunks per row (8 or 16)
  __shared__ alignas(16) u16 As[128 * BK];
  __shared__ alignas(16) u16 Bs[128 * BK];
  const int t = threadIdx.x;
  const int lane = t & 63, w = t >> 6;
  const int wm = w >> 1, wn = w & 1;
  const int cc = lane & 15, quad = lane >> 4;

  // 2D-region XCD decode (bijective: gridDim.x % 8 == 0, rw | gx, rw | q)
  const int i   = blockIdx.x;
  const int xcd = i & 7;
  const int s   = i >> 3;
  const int rcols = gx / rw;
  const int rh  = (gridDim.x >> 3) / rw;
  const int rcol = xcd % rcols, rrow = xcd / rcols;
  const int lx = s % rw, ly = s / rw;
  const int n0 = (rcol * rw + lx) * 128;
  const int m0 = (rrow * rh + ly) * 128;

  const f32x4 fz = {0.f, 0.f, 0.f, 0.f};
  f32x4 acc[4][4];
#pragma unroll
  for (int i2 = 0; i2 < 4; ++i2)
#pragma unroll
    for (int j = 0; j < 4; ++j) acc[i2][j] = fz;

  const int off0 = t * 16;
  for (int k0 = 0; k0 < K; k0 += BK) {
#pragma unroll
    for (int r = 0; r < BK / 16; ++r) {
      const int off = r * 4096 + off0;
      const int row = off / ROWB;
      const int cl  = ((off >> 4) & (CH - 1)) ^ (row & (CH - 1));
      async16(A  + (size_t)(m0 + row) * K + k0 + cl * 8, (char*)As + off);
      async16(BT + (size_t)(n0 + row) * K + k0 + cl * 8, (char*)Bs + off);
    }
    __syncthreads();   // drains vmcnt (all waves) -> tiles resident
#pragma unroll
    for (int kk = 0; kk < BK / 32; ++kk) {
      short8v a[4], b[4];
#pragma unroll
      for (int i2 = 0; i2 < 4; ++i2)
        a[i2] = *(const short8v*)(As + (wm * 64 + i2 * 16 + cc) * BK +
                                  (((kk * 4 + quad) ^ (cc & (CH - 1))) << 3));
#pragma unroll
      for (int j = 0; j < 4; ++j)
        b[j] = *(const short8v*)(Bs + (wn * 64 + j * 16 + cc) * BK +
                                 (((kk * 4 + quad) ^ (cc & (CH - 1))) << 3));
#pragma unroll
      for (int i2 = 0; i2 < 4; ++i2)
#pragma unroll
        for (int j = 0; j < 4; ++j) acc[i2][j] = mfma_b(a[i2], b[j], acc[i2][j]);
    }
    __syncthreads();
  }

#pragma unroll
  for (int i2 = 0; i2 < 4; ++i2) {
    const int row = m0 + wm * 64 + i2 * 16 + quad * 4;
#pragma unroll
    for (int j = 0; j < 4; ++j) {
      const int col = n0 + wn * 64 + j * 16 + cc;
      f32x4 v = accfence(acc[i2][j]);
#pragma unroll
      for (int r = 0; r < 4; ++r) {
        const size_t idx = (size_t)(row + r) * N + col;
        float val = v[r];
        if (mode == 0) {
          outb[idx] = f2bf(val);
        } else if (mode == 2) {
          val += bias[col];
          // gelu, tanh form: x * sigmoid(1.5957691*(x + 0.044715 x^3))
          const float zz = val * fmaf(val * val, 0.044715f, 1.0f);
          const float e = __builtin_amdgcn_exp2f(-2.3022082f * zz);
          val = val * __builtin_amdgcn_rcpf(1.0f + e);
          outb[idx] = f2bf(val);
        } else {  // 1 or 3: fp32 residual epilogue
          outf[idx] = val + bias[col] + res[idx];
        }
      }
    }
  }
}

// ---------------------------------------------------------------------------
// Causal flash attention (R7 structure): uniform chunk-pair blocks,
// XCD-local decode, double-buffered async16 K/V staging (one __syncthreads
// per K-tile; next tile staged right after it, in flight through compute).
// ---------------------------------------------------------------------------
__global__ __launch_bounds__(256, 2) void attn_kernel(const u16* __restrict__ qkv,
    const u16* __restrict__ vt, u16* __restrict__ outp) {
  const int f  = blockIdx.x;            // 0..511
  const int p  = (f >> 3) & 7;          // chunk pair: {p, 15-p}
  const int g  = ((f >> 6) << 3) | (f & 7);   // (b,h) group, XCD-local mod 8
  const int hh = g & 15, bb = g >> 4;
  const int t = threadIdx.x, lane = t & 63, w = t >> 6;
  const int cc = lane & 15, quad = lane >> 4;

  __shared__ alignas(16) u16 Ks[2][64 * 64];   // [key][d], swizzled, 8KB each
  __shared__ alignas(16) u16 Vs[2][64 * 64];   // [d][key], swizzled
  __shared__ alignas(16) u16 Ps[4][16 * 64];   // per-wave P round-trip, swizzled

  const u16* kbase = qkv + (size_t)bb * N_ * 3072 + 1024 + hh * DH_;
  const u16* vbase = vt + ((size_t)(bb * H_ + hh)) * DH_ * N_;

  const int soff0 = t * 16;
#pragma unroll
  for (int r = 0; r < 2; ++r) {      // prologue: K/V tile 0 -> buf 0
    const int off = r * 4096 + soff0;
    const int row = off >> 7;
    const int cl  = ((off >> 4) & 7) ^ (row & 7);
    async16(kbase + (size_t)row * 3072 + cl * 8, (char*)Ks[0] + off);
    async16(vbase + (size_t)row * N_ + cl * 8,   (char*)Vs[0] + off);
  }

  const f32x4 fz = {0.f, 0.f, 0.f, 0.f};
  const float C1 = 0.18033688011112042f;    // 0.125 * log2(e)
  const float C2 = -11.541560327111707f;    // -8 * log2(e)

  int bufc = 0;
#pragma unroll
  for (int ci = 0; ci < 2; ++ci) {
    const int qc = ci ? 15 - p : p;
    const int q0 = qc * 128;
    const int ktmax = 2 * qc + 1;

    short8v qa[2][2];
#pragma unroll
    for (int s = 0; s < 2; ++s)
#pragma unroll
      for (int h = 0; h < 2; ++h)
        qa[s][h] = *(const short8v*)(qkv +
            (size_t)(bb * N_ + q0 + s * 64 + w * 16 + cc) * 3072 +
            hh * DH_ + h * 32 + quad * 8);

    f32x4 of[2][4];
    float rs[2][4];
#pragma unroll
    for (int s = 0; s < 2; ++s)
#pragma unroll
      for (int n = 0; n < 4; ++n) { of[s][n] = fz; rs[s][n] = 0.f; }

    for (int kt = 0; kt <= ktmax; ++kt) {
      const int k0 = kt * 64;
      const int cur = bufc & 1;
      __syncthreads();   // drains async16 for buf cur; buf cur^1 is now free

      if ((kt < ktmax) | (ci == 0)) {
        const int k1 = (kt < ktmax) ? k0 + 64 : 0;
#pragma unroll
        for (int r = 0; r < 2; ++r) {
          const int off = r * 4096 + soff0;
          const int row = off >> 7;
          const int cl  = ((off >> 4) & 7) ^ (row & 7);
          async16(kbase + (size_t)(k1 + row) * 3072 + cl * 8, (char*)Ks[cur ^ 1] + off);
          async16(vbase + (size_t)row * N_ + k1 + cl * 8,     (char*)Vs[cur ^ 1] + off);
        }
      }

      const u16* KsB = Ks[cur];
      const u16* VsB = Vs[cur];
      short8v kb[4][2], vb[4][2];
#pragma unroll
      for (int j = 0; j < 4; ++j)
#pragma unroll
        for (int h = 0; h < 2; ++h) {
          kb[j][h] = *(const short8v*)(KsB + (j * 16 + cc) * 64 + SWZ8(cc, h * 4 + quad));
          vb[j][h] = *(const short8v*)(VsB + (j * 16 + cc) * 64 + SWZ8(cc, h * 4 + quad));
        }

#pragma unroll
      for (int s = 0; s < 2; ++s) {
        const int Rbase = q0 + s * 64 + w * 16;
        if (k0 > Rbase + 15) continue;

        f32x4 sr[4];
#pragma unroll
        for (int j = 0; j < 4; ++j) {
          f32x4 z = fz;
          z = mfma_b_vc(qa[s][0], kb[j][0], z);
          z = mfma_b(qa[s][1], kb[j][1], z);
          sr[j] = accfence(z);
        }

        if (k0 + 63 > Rbase) {
#pragma unroll
          for (int j = 0; j < 4; ++j) {
            const int kcol = k0 + j * 16 + cc;
#pragma unroll
            for (int r = 0; r < 4; ++r) {
              float pv = __builtin_amdgcn_exp2f(fmaf(sr[j][r], C1, C2));
              pv = (kcol <= Rbase + quad * 4 + r) ? pv : 0.f;
              sr[j][r] = pv;
              rs[s][r] += pv;
            }
          }
        } else {
#pragma unroll
          for (int j = 0; j < 4; ++j)
#pragma unroll
            for (int r = 0; r < 4; ++r) {
              const float pv = __builtin_amdgcn_exp2f(fmaf(sr[j][r], C1, C2));
              sr[j][r] = pv;
              rs[s][r] += pv;
            }
        }

#pragma unroll
        for (int j = 0; j < 4; ++j)
#pragma unroll
          for (int r = 0; r < 4; ++r) {
            union { float f; unsigned u; } cv; cv.f = sr[j][r];
            const int rho = quad * 4 + r;
            const int Lc  = j * 2 + (cc >> 3);
            Ps[w][rho * 64 + (((Lc ^ (rho & 7)) << 3) | (cc & 7))] =
                (u16)((cv.u + 0x8000u) >> 16);
          }
        const short8v pa0 = *(const short8v*)(&Ps[w][cc * 64 + SWZ8(cc, quad)]);
        const short8v pa1 = *(const short8v*)(&Ps[w][cc * 64 + SWZ8(cc, 4 + quad)]);
#pragma unroll
        for (int n = 0; n < 4; ++n) {
          of[s][n] = mfma_b(pa0, vb[n][0], of[s][n]);
          of[s][n] = mfma_b(pa1, vb[n][1], of[s][n]);
        }
      }
      ++bufc;
    }

#pragma unroll
    for (int o = 1; o < 16; o <<= 1)
#pragma unroll
      for (int s = 0; s < 2; ++s)
#pragma unroll
        for (int r = 0; r < 4; ++r) rs[s][r] += __shfl_xor(rs[s][r], o);

#pragma unroll
    for (int s = 0; s < 2; ++s) {
      float inv[4];
#pragma unroll
      for (int r = 0; r < 4; ++r) inv[r] = 1.0f / rs[s][r];
#pragma unroll
      for (int n = 0; n < 4; ++n) {
        f32x4 o = accfence(of[s][n]);
#pragma unroll
        for (int r = 0; r < 4; ++r) {
          const size_t row = (size_t)(bb * N_ + q0 + s * 64 + w * 16 + quad * 4 + r);
          outp[row * 1024 + hh * DH_ + n * 16 + cc] = f2bf(o[r] * inv[r]);
        }
      }
    }
  }
}

// ---------------------------------------------------------------------------
// Halt head: hout[b] = mean_n(x[b]) @ w_halt + b_halt
// ---------------------------------------------------------------------------
__global__ void halt_init(float* __restrict__ hout, const float* __restrict__ bh) {
  if (threadIdx.x < B_) hout[threadIdx.x] = bh[0];
}

__global__ __launch_bounds__(256) void halt_partial(const float* __restrict__ xf,
    const float* __restrict__ wh, float* __restrict__ hout) {
  const int bb = blockIdx.y, sl = blockIdx.x;
  const size_t base = ((size_t)bb * N_ + sl * 64) * D_;
  float p = 0.f;
  for (int e = threadIdx.x; e < 64 * D_; e += 256)
    p += xf[base + e] * wh[e & (D_ - 1)];
#pragma unroll
  for (int o = 32; o >= 1; o >>= 1) p += __shfl_xor(p, o);
  __shared__ float red[4];
  const int w = threadIdx.x >> 6;
  if ((threadIdx.x & 63) == 0) red[w] = p;
  __syncthreads();
  if (threadIdx.x == 0)
    atomicAdd(&hout[bb], (red[0] + red[1] + red[2] + red[3]) * (1.0f / N_));
}

// ---------------------------------------------------------------------------
extern "C" void kernel_launch(void* const* d_in, const int* in_sizes, int n_in,
                              void* d_out, int out_size, void* d_ws, size_t ws_size,
                              hipStream_t stream) {
  (void)in_sizes; (void)n_in; (void)out_size; (void)ws_size;
  const float* x      = (const float*)d_in[0];
  const float* ln1_g  = (const float*)d_in[1];
  const float* ln1_b  = (const float*)d_in[2];
  const float* w_qkv  = (const float*)d_in[3];
  const float* w_out  = (const float*)d_in[4];
  const float* b_out  = (const float*)d_in[5];
  const float* ln2_g  = (const float*)d_in[6];
  const float* ln2_b  = (const float*)d_in[7];
  const float* w_ff1  = (const float*)d_in[8];
  const float* b_ff1  = (const float*)d_in[9];
  const float* w_ff2  = (const float*)d_in[10];
  const float* b_ff2  = (const float*)d_in[11];
  const float* w_halt = (const float*)d_in[12];
  const float* b_halt = (const float*)d_in[13];

  float* out_x    = (float*)d_out;                       // [8192,1024] fp32
  float* out_halt = out_x + (size_t)ROWS_ * D_;          // [4]

  // Workspace layout (bytes). Persistent transposed bf16 weights, then a
  // liveness-overlapped scratch region. Total ~104 MB.
  char* ws = (char*)d_ws;
  u16* wqkvT = (u16*)(ws + 0);           //  6291456  [3072,1024]
  u16* woutT = (u16*)(ws + 6291456);     //  2097152  [1024,1024]
  u16* wff1T = (u16*)(ws + 8388608);     //  8388608  [4096,1024]
  u16* wff2T = (u16*)(ws + 16777216);    //  8388608  [1024,4096]
  char* RB   = ws + 25165824;
  u16* qkvb  = (u16*)(RB);               // 50331648  [8192,3072] (dead after attn)
  u16* h1    = (u16*)(RB + 50331648);    // 16777216  (dead after qkv gemm)
  u16* attno = h1;                       // aliases h1 (dead after out-proj)
  u16* vtb   = (u16*)(RB + 67108864);    // 16777216  (dead after attn)
  u16* h2    = (u16*)(RB);               // aliases qkvb
  u16* ff1b  = (u16*)(RB + 16777216);    // 67108864  aliases vtb/attno tail

  const dim3 tb(32, 8);
  // 1) weights -> bf16 transposed (single launch)
  transpose_all<<<12288, tb, 0, stream>>>(w_qkv, w_out, w_ff1, w_ff2,
                                          wqkvT, woutT, wff1T, wff2T);
  // 2) LN1
  ln_kernel<<<ROWS_, 256, 0, stream>>>(x, ln1_g, ln1_b, h1);
  // 3) qkv = h1 @ w_qkv -> bf16. grid 24x64=1536 tiles; region 12x16
  gemm_bt<64><<<1536, 256, 0, stream>>>(h1, wqkvT, 3072, 1024, 0, 24, 12,
                                        nullptr, nullptr, nullptr, qkvb);
  // 4) V -> [b,h,d,n]
  transpose_v<<<dim3(64, 2, 64), tb, 0, stream>>>(qkvb, vtb);
  // 5) causal flash attention (uniform chunk-pair blocks, XCD-local decode)
  attn_kernel<<<dim3(512), 256, 0, stream>>>(qkvb, vtb, attno);
  // 6) x1 = attn @ w_out + b_out + x. grid 8x64=512 tiles; region 8x8; BK=64
  gemm_bt<64><<<512, 256, 0, stream>>>(attno, woutT, 1024, 1024, 1, 8, 8,
                                       b_out, x, out_x, nullptr);
  // 7) LN2
  ln_kernel<<<ROWS_, 256, 0, stream>>>(out_x, ln2_g, ln2_b, h2);
  // 8) ff1 = gelu(h2 @ w_ff1 + b_ff1) -> bf16. grid 32x64=2048; region 16x16
  gemm_bt<64><<<2048, 256, 0, stream>>>(h2, wff1T, 4096, 1024, 2, 32, 16,
                                        b_ff1, nullptr, nullptr, ff1b);
  // 9) x = ff1 @ w_ff2 + b_ff2 + x1. grid 8x64=512 tiles; region 8x8; BK=128
  gemm_bt<128><<<512, 256, 0, stream>>>(ff1b, wff2T, 1024, 4096, 3, 8, 8,
                                        b_ff2, out_x, out_x, nullptr);
  // 10) halt
  halt_init<<<1, 64, 0, stream>>>(out_halt, b_halt);
  halt_partial<<<dim3(32, 4), 256, 0, stream>>>(out_x, w_halt, out_halt);
}

// Round 12
// 496.291 us; speedup vs baseline: 1.1939x; 1.1687x over previous
//
#include <hip/hip_runtime.h>
#include <stdint.h>

// ---------------------------------------------------------------------------
// Fused transformer block: LN1 -> qkv -> causal flash attn -> out-proj(+res)
//                          -> LN2 -> gelu-FFN(+res, +halt) -> done
// bf16 MFMA (16x16x32) for all matmuls; fp32 residual stream.
// R17 = R14 banked config (560-580us, 3x reproduced) + halt head fused into
// ff2's epilogue (mode 3): each thread dots its 64 outputs with w_halt
// (4 hoisted wh loads), wave-shfl + LDS reduce (aliases dead As buffer ->
// no LDS growth), one atomicAdd per block. halt_partial's 32MB re-read of
// out_x is eliminated; halt_init seeds the accumulator before ff2.
//   - qkv BK64 1536 blocks, out-proj BK64, ff1 128^2 BK64, ff2 BK128.
//   - Cheap tanh-gelu epilogue (R8); 2D-region XCD decode (R9);
//     uniform chunk-pair attn w/ XCD-local decode (R7).
// ---------------------------------------------------------------------------

typedef unsigned short u16;
typedef __attribute__((ext_vector_type(8))) short short8v;   // 8 bf16 = 4 VGPR
typedef __attribute__((ext_vector_type(4))) float f32x4;     // MFMA C/D frag
typedef __attribute__((ext_vector_type(4))) u16 u16x4;

#define B_ 4
#define N_ 2048
#define D_ 1024
#define H_ 16
#define DH_ 64
#define ROWS_ (B_ * N_)   // 8192

__device__ __forceinline__ u16 f2bf(float f) {
  union { float f; unsigned u; } v; v.f = f;
  unsigned r = v.u + 0x7fffu + ((v.u >> 16) & 1u);   // RNE
  return (u16)(r >> 16);
}

// MFMA via inline asm. C operand from a previous MFMA or far-away init.
__device__ __forceinline__ f32x4 mfma_b(short8v a, short8v b, f32x4 c) {
  asm volatile("v_mfma_f32_16x16x32_bf16 %0, %1, %2, %0" : "+v"(c) : "v"(a), "v"(b));
  return c;
}
// C freshly VALU-written (zero init): cover the write->MFMA-read hazard.
__device__ __forceinline__ f32x4 mfma_b_vc(short8v a, short8v b, f32x4 c) {
  asm volatile("s_nop 1\n\tv_mfma_f32_16x16x32_bf16 %0, %1, %2, %0" : "+v"(c) : "v"(a), "v"(b));
  return c;
}
// Pass-through fence before VALU reads of MFMA results.
__device__ __forceinline__ f32x4 accfence(f32x4 v) {
  asm volatile("s_nop 7" : "+v"(v));
  return v;
}

// async global->LDS, 16B per lane. LDS side must be wave-uniform base + lane*16.
__device__ __forceinline__ void async16(const void* g, void* l) {
  __builtin_amdgcn_global_load_lds((__attribute__((address_space(1))) unsigned int*)g,
                                   (__attribute__((address_space(3))) unsigned int*)l,
                                   16, 0, 0);
}

// XOR swizzle for LDS tiles with CH 16B-chunks per row: physical chunk p of
// row r holds logical chunk p ^ (r & (CH-1)). Staging writes at lane*16
// (async16-compatible); reads of a fixed logical chunk across rows spread
// over CH distinct 16B slots.
#define SWZ8(row, chunk) ((((chunk) ^ ((row) & 7)) << 3))   // u16 offset in row

// ---------------------------------------------------------------------------
// LayerNorm over D=1024, fp32 in -> bf16 out. One block (256 thr) per row.
// ---------------------------------------------------------------------------
__global__ __launch_bounds__(256) void ln_kernel(const float* __restrict__ x,
    const float* __restrict__ gam, const float* __restrict__ bet,
    u16* __restrict__ out) {
  const int row = blockIdx.x;
  const int t = threadIdx.x;
  const float4 v = ((const float4*)(x + (size_t)row * D_))[t];
  float s  = v.x + v.y + v.z + v.w;
  float ss = v.x*v.x + v.y*v.y + v.z*v.z + v.w*v.w;
#pragma unroll
  for (int o = 32; o >= 1; o >>= 1) { s += __shfl_xor(s, o); ss += __shfl_xor(ss, o); }
  __shared__ float red[8];
  const int w = t >> 6;
  if ((t & 63) == 0) { red[w] = s; red[4 + w] = ss; }
  __syncthreads();
  s  = red[0] + red[1] + red[2] + red[3];
  ss = red[4] + red[5] + red[6] + red[7];
  const float mean = s * (1.0f / D_);
  const float var  = ss * (1.0f / D_) - mean * mean;
  const float rstd = rsqrtf(var + 1e-5f);
  const float4 g4 = ((const float4*)gam)[t];
  const float4 b4 = ((const float4*)bet)[t];
  u16x4 o4;
  o4.x = f2bf((v.x - mean) * rstd * g4.x + b4.x);
  o4.y = f2bf((v.y - mean) * rstd * g4.y + b4.y);
  o4.z = f2bf((v.z - mean) * rstd * g4.z + b4.z);
  o4.w = f2bf((v.w - mean) * rstd * g4.w + b4.w);
  *(u16x4*)(out + (size_t)row * D_ + t * 4) = o4;
}

// ---------------------------------------------------------------------------
// All 4 weight transposes in one launch: W[K][N] fp32 -> WT[N][K] bf16.
// ---------------------------------------------------------------------------
__global__ __launch_bounds__(256) void transpose_all(
    const float* __restrict__ wqkv, const float* __restrict__ wout,
    const float* __restrict__ wff1, const float* __restrict__ wff2,
    u16* __restrict__ wqkvT, u16* __restrict__ woutT,
    u16* __restrict__ wff1T, u16* __restrict__ wff2T) {
  __shared__ float tile[32][33];
  int id = blockIdx.x;
  const float* W; u16* WT; int K, N, nt, kt;
  if (id < 3072)      { W = wqkv; WT = wqkvT; K = 1024; N = 3072; nt = id % 96;  kt = id / 96; }
  else if (id < 4096) { id -= 3072; W = wout; WT = woutT; K = 1024; N = 1024; nt = id % 32;  kt = id / 32; }
  else if (id < 8192) { id -= 4096; W = wff1; WT = wff1T; K = 1024; N = 4096; nt = id % 128; kt = id / 128; }
  else                { id -= 8192; W = wff2; WT = wff2T; K = 4096; N = 1024; nt = id % 32;  kt = id / 32; }
  const int n0 = nt * 32, k0 = kt * 32;
  const int tx = threadIdx.x, ty = threadIdx.y;
#pragma unroll
  for (int i = 0; i < 4; ++i)
    tile[ty + i * 8][tx] = W[(size_t)(k0 + ty + i * 8) * N + n0 + tx];
  __syncthreads();
#pragma unroll
  for (int i = 0; i < 4; ++i)
    WT[(size_t)(n0 + ty + i * 8) * K + k0 + tx] = f2bf(tile[tx][ty + i * 8]);
}

// V transpose: qkv bf16 v-part -> vt[b][h][d][n] so PV A-frags read contiguous.
__global__ __launch_bounds__(256) void transpose_v(const u16* __restrict__ qkv,
    u16* __restrict__ vt) {
  __shared__ u16 tile[32][33];
  const int bh = blockIdx.z;
  const int bb = bh >> 4, hh = bh & 15;
  const int n0 = blockIdx.x * 32, d0 = blockIdx.y * 32;
  const int tx = threadIdx.x, ty = threadIdx.y;
#pragma unroll
  for (int i = 0; i < 4; ++i)
    tile[ty + i * 8][tx] =
        qkv[(size_t)(bb * N_ + n0 + ty + i * 8) * 3072 + 2048 + hh * DH_ + d0 + tx];
  __syncthreads();
#pragma unroll
  for (int i = 0; i < 4; ++i)
    vt[((size_t)bh * DH_ + d0 + ty + i * 8) * N_ + n0 + tx] = tile[tx][ty + i * 8];
}

// ---------------------------------------------------------------------------
// bf16 MFMA GEMM: 128x128 block tile, templated BK (64 or 128), XOR-swizzled
// LDS, single-buffered stage->sync->compute->sync (drain covered by TLP;
// __syncthreads = per-wave vmcnt(0) + barrier = globally safe for the
// cross-wave LDS fill). 4 waves 2x2, each wave 4x4 16x16 frags.
// 1-D grid with 2D-region XCD decode: block id i -> xcd = i&7 owns a
// rw x rh region of the (n,m) tile grid, keeping operand panels in the
// XCD's private L2.
// Epilogue modes:
//   0: store bf16            2: gelu(C+bias) -> bf16   (tanh-form, exp2+rcp)
//   1: C + bias + res -> fp32
//   3: C + bias + res -> fp32, PLUS fused halt partial: block-reduced
//      sum(out*wh[col]) atomicAdd'ed into hout[batch] (scaled 1/N_).
// ---------------------------------------------------------------------------
template <int BK>
__global__ __launch_bounds__(256) void gemm_bt(
    const u16* __restrict__ A, const u16* __restrict__ BT,
    int N, int K, int mode, int gx, int rw,
    const float* __restrict__ bias, const float* __restrict__ res,
    float* __restrict__ outf, u16* __restrict__ outb,
    const float* __restrict__ wh, float* __restrict__ hout) {
  constexpr int ROWB = BK * 2;       // bytes per LDS row
  constexpr int CH   = BK / 8;       // 16B chunks per row (8 or 16)
  __shared__ alignas(16) u16 As[128 * BK];
  __shared__ alignas(16) u16 Bs[128 * BK];
  const int t = threadIdx.x;
  const int lane = t & 63, w = t >> 6;
  const int wm = w >> 1, wn = w & 1;
  const int cc = lane & 15, quad = lane >> 4;

  // 2D-region XCD decode (bijective: gridDim.x % 8 == 0, rw | gx, rw | q)
  const int i   = blockIdx.x;
  const int xcd = i & 7;
  const int s   = i >> 3;
  const int rcols = gx / rw;
  const int rh  = (gridDim.x >> 3) / rw;
  const int rcol = xcd % rcols, rrow = xcd / rcols;
  const int lx = s % rw, ly = s / rw;
  const int n0 = (rcol * rw + lx) * 128;
  const int m0 = (rrow * rh + ly) * 128;

  const f32x4 fz = {0.f, 0.f, 0.f, 0.f};
  f32x4 acc[4][4];
#pragma unroll
  for (int i2 = 0; i2 < 4; ++i2)
#pragma unroll
    for (int j = 0; j < 4; ++j) acc[i2][j] = fz;

  const int off0 = t * 16;
  for (int k0 = 0; k0 < K; k0 += BK) {
#pragma unroll
    for (int r = 0; r < BK / 16; ++r) {
      const int off = r * 4096 + off0;
      const int row = off / ROWB;
      const int cl  = ((off >> 4) & (CH - 1)) ^ (row & (CH - 1));
      async16(A  + (size_t)(m0 + row) * K + k0 + cl * 8, (char*)As + off);
      async16(BT + (size_t)(n0 + row) * K + k0 + cl * 8, (char*)Bs + off);
    }
    __syncthreads();   // drains vmcnt (all waves) -> tiles resident
#pragma unroll
    for (int kk = 0; kk < BK / 32; ++kk) {
      short8v a[4], b[4];
#pragma unroll
      for (int i2 = 0; i2 < 4; ++i2)
        a[i2] = *(const short8v*)(As + (wm * 64 + i2 * 16 + cc) * BK +
                                  (((kk * 4 + quad) ^ (cc & (CH - 1))) << 3));
#pragma unroll
      for (int j = 0; j < 4; ++j)
        b[j] = *(const short8v*)(Bs + (wn * 64 + j * 16 + cc) * BK +
                                 (((kk * 4 + quad) ^ (cc & (CH - 1))) << 3));
#pragma unroll
      for (int i2 = 0; i2 < 4; ++i2)
#pragma unroll
        for (int j = 0; j < 4; ++j) acc[i2][j] = mfma_b(a[i2], b[j], acc[i2][j]);
    }
    __syncthreads();
  }

  // halt weights for this thread's 4 columns (cols independent of i2, r)
  float wh4[4] = {0.f, 0.f, 0.f, 0.f};
  if (mode == 3) {
#pragma unroll
    for (int j = 0; j < 4; ++j) wh4[j] = wh[n0 + wn * 64 + j * 16 + cc];
  }
  float hp = 0.f;

#pragma unroll
  for (int i2 = 0; i2 < 4; ++i2) {
    const int row = m0 + wm * 64 + i2 * 16 + quad * 4;
#pragma unroll
    for (int j = 0; j < 4; ++j) {
      const int col = n0 + wn * 64 + j * 16 + cc;
      f32x4 v = accfence(acc[i2][j]);
#pragma unroll
      for (int r = 0; r < 4; ++r) {
        const size_t idx = (size_t)(row + r) * N + col;
        float val = v[r];
        if (mode == 0) {
          outb[idx] = f2bf(val);
        } else if (mode == 2) {
          val += bias[col];
          // gelu, tanh form: x * sigmoid(1.5957691*(x + 0.044715 x^3))
          const float zz = val * fmaf(val * val, 0.044715f, 1.0f);
          const float e = __builtin_amdgcn_exp2f(-2.3022082f * zz);
          val = val * __builtin_amdgcn_rcpf(1.0f + e);
          outb[idx] = f2bf(val);
        } else {  // 1 or 3: fp32 residual epilogue
          const float ov = val + bias[col] + res[idx];
          outf[idx] = ov;
          if (mode == 3) hp = fmaf(ov, wh4[j], hp);
        }
      }
    }
  }

  // fused halt partial (mode 3): block reduce (alias dead As) + one atomic.
  // Tile rows m0..m0+127 lie in one batch (2048 % 128 == 0).
  if (mode == 3) {
#pragma unroll
    for (int o = 32; o >= 1; o >>= 1) hp += __shfl_xor(hp, o);
    float* hred = (float*)As;   // K-loop done; trailing sync passed by all
    if (lane == 0) hred[w] = hp;
    __syncthreads();
    if (t == 0)
      atomicAdd(&hout[m0 >> 11],
                (hred[0] + hred[1] + hred[2] + hred[3]) * (1.0f / N_));
  }
}

// ---------------------------------------------------------------------------
// Causal flash attention (R7 structure): uniform chunk-pair blocks,
// XCD-local decode, double-buffered async16 K/V staging (one __syncthreads
// per K-tile; next tile staged right after it, in flight through compute).
// ---------------------------------------------------------------------------
__global__ __launch_bounds__(256, 2) void attn_kernel(const u16* __restrict__ qkv,
    const u16* __restrict__ vt, u16* __restrict__ outp) {
  const int f  = blockIdx.x;            // 0..511
  const int p  = (f >> 3) & 7;          // chunk pair: {p, 15-p}
  const int g  = ((f >> 6) << 3) | (f & 7);   // (b,h) group, XCD-local mod 8
  const int hh = g & 15, bb = g >> 4;
  const int t = threadIdx.x, lane = t & 63, w = t >> 6;
  const int cc = lane & 15, quad = lane >> 4;

  __shared__ alignas(16) u16 Ks[2][64 * 64];   // [key][d], swizzled, 8KB each
  __shared__ alignas(16) u16 Vs[2][64 * 64];   // [d][key], swizzled
  __shared__ alignas(16) u16 Ps[4][16 * 64];   // per-wave P round-trip, swizzled

  const u16* kbase = qkv + (size_t)bb * N_ * 3072 + 1024 + hh * DH_;
  const u16* vbase = vt + ((size_t)(bb * H_ + hh)) * DH_ * N_;

  const int soff0 = t * 16;
#pragma unroll
  for (int r = 0; r < 2; ++r) {      // prologue: K/V tile 0 -> buf 0
    const int off = r * 4096 + soff0;
    const int row = off >> 7;
    const int cl  = ((off >> 4) & 7) ^ (row & 7);
    async16(kbase + (size_t)row * 3072 + cl * 8, (char*)Ks[0] + off);
    async16(vbase + (size_t)row * N_ + cl * 8,   (char*)Vs[0] + off);
  }

  const f32x4 fz = {0.f, 0.f, 0.f, 0.f};
  const float C1 = 0.18033688011112042f;    // 0.125 * log2(e)
  const float C2 = -11.541560327111707f;    // -8 * log2(e)

  int bufc = 0;
#pragma unroll
  for (int ci = 0; ci < 2; ++ci) {
    const int qc = ci ? 15 - p : p;
    const int q0 = qc * 128;
    const int ktmax = 2 * qc + 1;

    short8v qa[2][2];
#pragma unroll
    for (int s = 0; s < 2; ++s)
#pragma unroll
      for (int h = 0; h < 2; ++h)
        qa[s][h] = *(const short8v*)(qkv +
            (size_t)(bb * N_ + q0 + s * 64 + w * 16 + cc) * 3072 +
            hh * DH_ + h * 32 + quad * 8);

    f32x4 of[2][4];
    float rs[2][4];
#pragma unroll
    for (int s = 0; s < 2; ++s)
#pragma unroll
      for (int n = 0; n < 4; ++n) { of[s][n] = fz; rs[s][n] = 0.f; }

    for (int kt = 0; kt <= ktmax; ++kt) {
      const int k0 = kt * 64;
      const int cur = bufc & 1;
      __syncthreads();   // drains async16 for buf cur; buf cur^1 is now free

      if ((kt < ktmax) | (ci == 0)) {
        const int k1 = (kt < ktmax) ? k0 + 64 : 0;
#pragma unroll
        for (int r = 0; r < 2; ++r) {
          const int off = r * 4096 + soff0;
          const int row = off >> 7;
          const int cl  = ((off >> 4) & 7) ^ (row & 7);
          async16(kbase + (size_t)(k1 + row) * 3072 + cl * 8, (char*)Ks[cur ^ 1] + off);
          async16(vbase + (size_t)row * N_ + k1 + cl * 8,     (char*)Vs[cur ^ 1] + off);
        }
      }

      const u16* KsB = Ks[cur];
      const u16* VsB = Vs[cur];
      short8v kb[4][2], vb[4][2];
#pragma unroll
      for (int j = 0; j < 4; ++j)
#pragma unroll
        for (int h = 0; h < 2; ++h) {
          kb[j][h] = *(const short8v*)(KsB + (j * 16 + cc) * 64 + SWZ8(cc, h * 4 + quad));
          vb[j][h] = *(const short8v*)(VsB + (j * 16 + cc) * 64 + SWZ8(cc, h * 4 + quad));
        }

#pragma unroll
      for (int s = 0; s < 2; ++s) {
        const int Rbase = q0 + s * 64 + w * 16;
        if (k0 > Rbase + 15) continue;

        f32x4 sr[4];
#pragma unroll
        for (int j = 0; j < 4; ++j) {
          f32x4 z = fz;
          z = mfma_b_vc(qa[s][0], kb[j][0], z);
          z = mfma_b(qa[s][1], kb[j][1], z);
          sr[j] = accfence(z);
        }

        if (k0 + 63 > Rbase) {
#pragma unroll
          for (int j = 0; j < 4; ++j) {
            const int kcol = k0 + j * 16 + cc;
#pragma unroll
            for (int r = 0; r < 4; ++r) {
              float pv = __builtin_amdgcn_exp2f(fmaf(sr[j][r], C1, C2));
              pv = (kcol <= Rbase + quad * 4 + r) ? pv : 0.f;
              sr[j][r] = pv;
              rs[s][r] += pv;
            }
          }
        } else {
#pragma unroll
          for (int j = 0; j < 4; ++j)
#pragma unroll
            for (int r = 0; r < 4; ++r) {
              const float pv = __builtin_amdgcn_exp2f(fmaf(sr[j][r], C1, C2));
              sr[j][r] = pv;
              rs[s][r] += pv;
            }
        }

#pragma unroll
        for (int j = 0; j < 4; ++j)
#pragma unroll
          for (int r = 0; r < 4; ++r) {
            union { float f; unsigned u; } cv; cv.f = sr[j][r];
            const int rho = quad * 4 + r;
            const int Lc  = j * 2 + (cc >> 3);
            Ps[w][rho * 64 + (((Lc ^ (rho & 7)) << 3) | (cc & 7))] =
                (u16)((cv.u + 0x8000u) >> 16);
          }
        const short8v pa0 = *(const short8v*)(&Ps[w][cc * 64 + SWZ8(cc, quad)]);
        const short8v pa1 = *(const short8v*)(&Ps[w][cc * 64 + SWZ8(cc, 4 + quad)]);
#pragma unroll
        for (int n = 0; n < 4; ++n) {
          of[s][n] = mfma_b(pa0, vb[n][0], of[s][n]);
          of[s][n] = mfma_b(pa1, vb[n][1], of[s][n]);
        }
      }
      ++bufc;
    }

#pragma unroll
    for (int o = 1; o < 16; o <<= 1)
#pragma unroll
      for (int s = 0; s < 2; ++s)
#pragma unroll
        for (int r = 0; r < 4; ++r) rs[s][r] += __shfl_xor(rs[s][r], o);

#pragma unroll
    for (int s = 0; s < 2; ++s) {
      float inv[4];
#pragma unroll
      for (int r = 0; r < 4; ++r) inv[r] = 1.0f / rs[s][r];
#pragma unroll
      for (int n = 0; n < 4; ++n) {
        f32x4 o = accfence(of[s][n]);
#pragma unroll
        for (int r = 0; r < 4; ++r) {
          const size_t row = (size_t)(bb * N_ + q0 + s * 64 + w * 16 + quad * 4 + r);
          outp[row * 1024 + hh * DH_ + n * 16 + cc] = f2bf(o[r] * inv[r]);
        }
      }
    }
  }
}

// ---------------------------------------------------------------------------
// Halt seed: hout[b] = b_halt (ff2's fused epilogue atomicAdds the rest).
// ---------------------------------------------------------------------------
__global__ void halt_init(float* __restrict__ hout, const float* __restrict__ bh) {
  if (threadIdx.x < B_) hout[threadIdx.x] = bh[0];
}

// ---------------------------------------------------------------------------
extern "C" void kernel_launch(void* const* d_in, const int* in_sizes, int n_in,
                              void* d_out, int out_size, void* d_ws, size_t ws_size,
                              hipStream_t stream) {
  (void)in_sizes; (void)n_in; (void)out_size; (void)ws_size;
  const float* x      = (const float*)d_in[0];
  const float* ln1_g  = (const float*)d_in[1];
  const float* ln1_b  = (const float*)d_in[2];
  const float* w_qkv  = (const float*)d_in[3];
  const float* w_out  = (const float*)d_in[4];
  const float* b_out  = (const float*)d_in[5];
  const float* ln2_g  = (const float*)d_in[6];
  const float* ln2_b  = (const float*)d_in[7];
  const float* w_ff1  = (const float*)d_in[8];
  const float* b_ff1  = (const float*)d_in[9];
  const float* w_ff2  = (const float*)d_in[10];
  const float* b_ff2  = (const float*)d_in[11];
  const float* w_halt = (const float*)d_in[12];
  const float* b_halt = (const float*)d_in[13];

  float* out_x    = (float*)d_out;                       // [8192,1024] fp32
  float* out_halt = out_x + (size_t)ROWS_ * D_;          // [4]

  // Workspace layout (bytes). Persistent transposed bf16 weights, then a
  // liveness-overlapped scratch region. Total ~104 MB.
  char* ws = (char*)d_ws;
  u16* wqkvT = (u16*)(ws + 0);           //  6291456  [3072,1024]
  u16* woutT = (u16*)(ws + 6291456);     //  2097152  [1024,1024]
  u16* wff1T = (u16*)(ws + 8388608);     //  8388608  [4096,1024]
  u16* wff2T = (u16*)(ws + 16777216);    //  8388608  [1024,4096]
  char* RB   = ws + 25165824;
  u16* qkvb  = (u16*)(RB);               // 50331648  [8192,3072] (dead after attn)
  u16* h1    = (u16*)(RB + 50331648);    // 16777216  (dead after qkv gemm)
  u16* attno = h1;                       // aliases h1 (dead after out-proj)
  u16* vtb   = (u16*)(RB + 67108864);    // 16777216  (dead after attn)
  u16* h2    = (u16*)(RB);               // aliases qkvb
  u16* ff1b  = (u16*)(RB + 16777216);    // 67108864  aliases vtb/attno tail

  const dim3 tb(32, 8);
  // 1) weights -> bf16 transposed (single launch)
  transpose_all<<<12288, tb, 0, stream>>>(w_qkv, w_out, w_ff1, w_ff2,
                                          wqkvT, woutT, wff1T, wff2T);
  // 2) LN1
  ln_kernel<<<ROWS_, 256, 0, stream>>>(x, ln1_g, ln1_b, h1);
  // 3) qkv = h1 @ w_qkv -> bf16. grid 24x64=1536 tiles; region 12x16
  gemm_bt<64><<<1536, 256, 0, stream>>>(h1, wqkvT, 3072, 1024, 0, 24, 12,
                                        nullptr, nullptr, nullptr, qkvb,
                                        nullptr, nullptr);
  // 4) V -> [b,h,d,n]
  transpose_v<<<dim3(64, 2, 64), tb, 0, stream>>>(qkvb, vtb);
  // 5) causal flash attention (uniform chunk-pair blocks, XCD-local decode)
  attn_kernel<<<dim3(512), 256, 0, stream>>>(qkvb, vtb, attno);
  // 6) x1 = attn @ w_out + b_out + x. grid 8x64=512 tiles; region 8x8; BK=64
  gemm_bt<64><<<512, 256, 0, stream>>>(attno, woutT, 1024, 1024, 1, 8, 8,
                                       b_out, x, out_x, nullptr,
                                       nullptr, nullptr);
  // 7) LN2
  ln_kernel<<<ROWS_, 256, 0, stream>>>(out_x, ln2_g, ln2_b, h2);
  // 8) ff1 = gelu(h2 @ w_ff1 + b_ff1) -> bf16. grid 32x64=2048; region 16x16
  gemm_bt<64><<<2048, 256, 0, stream>>>(h2, wff1T, 4096, 1024, 2, 32, 16,
                                        b_ff1, nullptr, nullptr, ff1b,
                                        nullptr, nullptr);
  // 9a) seed halt accumulator (must precede ff2's fused atomics)
  halt_init<<<1, 64, 0, stream>>>(out_halt, b_halt);
  // 9b) x = ff1 @ w_ff2 + b_ff2 + x1 (+fused halt). 512 tiles; 8x8; BK=128
  gemm_bt<128><<<512, 256, 0, stream>>>(ff1b, wff2T, 1024, 4096, 3, 8, 8,
                                        b_ff2, out_x, out_x, nullptr,
                                        w_halt, out_halt);
}